// Round 6
// baseline (279.813 us; speedup 1.0000x reference)
//
#include <hip/hip_runtime.h>
#include <hip/hip_bf16.h>

using short8   = __attribute__((ext_vector_type(8))) short;
using floatx4  = __attribute__((ext_vector_type(4))) float;
using floatx16 = __attribute__((ext_vector_type(16))) float;

#define KDIM 768
#define QSCALE 0.18033688011112042f   // 0.125 * log2(e)
#define N1 (8192 * 768)
#define N2 (2304 * 768)
#define N3 (768 * 768)

__device__ __forceinline__ short f2bf(float f) {
    union { float f; unsigned u; } v; v.f = f;
    unsigned r = v.u + 0x7fffu + ((v.u >> 16) & 1u);
    return (short)(r >> 16);
}

__device__ __forceinline__ unsigned pack2bf(float a, float b) {
    __hip_bfloat162 h = __float22bfloat162_rn(float2{a, b});
    union { __hip_bfloat162 h; unsigned u; } c; c.h = h;
    return c.u;
}

__device__ __forceinline__ float fast_exp2(float x) {
#if __has_builtin(__builtin_amdgcn_exp2f)
    return __builtin_amdgcn_exp2f(x);
#else
    return exp2f(x);
#endif
}

__device__ __forceinline__ void async16(const void* g, void* l) {
    __builtin_amdgcn_global_load_lds((const __attribute__((address_space(1))) void*)g,
                                     (__attribute__((address_space(3))) void*)l, 16, 0, 0);
}

// ---------------- fused fp32 -> bf16 convert for all three inputs ----------------
__global__ void cvt_all(const float* __restrict__ a, const float* __restrict__ b,
                        const float* __restrict__ c, short* __restrict__ oa,
                        short* __restrict__ ob, short* __restrict__ oc) {
    int i = (blockIdx.x * blockDim.x + threadIdx.x) * 4;
    const float* src; short* dst;
    if (i < N1)            { src = a + i;            dst = oa + i; }
    else if (i < N1 + N2)  { src = b + (i - N1);     dst = ob + (i - N1); }
    else if (i < N1+N2+N3) { src = c + (i - N1 - N2); dst = oc + (i - N1 - N2); }
    else return;
    float4 v = *(const float4*)src;
    short4 o;
    o.x = f2bf(v.x); o.y = f2bf(v.y); o.z = f2bf(v.z); o.w = f2bf(v.w);
    *(short4*)dst = o;
}

// ---------------- QKV GEMM: C[8192,2304] = X @ W^T, scatter to Q/K/V [bh][s][64] ----------------
// XCD-aware remap: XCD c = fid%8 owns M-rows [8c, 8c+8) -> X slice 1.5 MB + W 3.5 MB fits its L2.
__global__ __launch_bounds__(256) void gemm_qkv(
    const short* __restrict__ X, const short* __restrict__ W,
    const float* __restrict__ bias,
    short* __restrict__ Qb, short* __restrict__ Kb, short* __restrict__ Vb)
{
    __shared__ short As[128 * 32];
    __shared__ short Bs[128 * 32];
    int tid = threadIdx.x;
    int w = tid >> 6, l = tid & 63;
    int lane16 = l & 15, quad = l >> 4;
    int wm = w & 1, wn = w >> 1;

    int fid = blockIdx.x + 18 * blockIdx.y;   // 0..1151, dispatch order
    int c = fid & 7, s = fid >> 3;            // s in 0..143
    int my = c * 8 + s / 18;                  // 0..63
    int nx = s % 18;                          // 0..17
    int m0 = my * 128, n0 = nx * 128;

    floatx4 acc[4][4] = {};

    int srow = w * 32 + (l >> 2);
    int scol = (l & 3) * 8;
    const short* Xg = X + (size_t)(m0 + srow) * KDIM + scol;
    const short* Wg = W + (size_t)(n0 + srow) * KDIM + scol;
    short* AsW = As + (w * 32) * 32;
    short* BsW = Bs + (w * 32) * 32;

    for (int kb = 0; kb < KDIM; kb += 32) {
        __syncthreads();
        async16(Xg + kb,              AsW);
        async16(Xg + kb + 16 * KDIM,  AsW + 16 * 32);
        async16(Wg + kb,              BsW);
        async16(Wg + kb + 16 * KDIM,  BsW + 16 * 32);
        __syncthreads();
        short8 a[4], b[4];
#pragma unroll
        for (int mt = 0; mt < 4; mt++) a[mt] = *(const short8*)(As + (wm * 64 + mt * 16 + lane16) * 32 + quad * 8);
#pragma unroll
        for (int nt = 0; nt < 4; nt++) b[nt] = *(const short8*)(Bs + (wn * 64 + nt * 16 + lane16) * 32 + quad * 8);
#pragma unroll
        for (int mt = 0; mt < 4; mt++)
#pragma unroll
            for (int nt = 0; nt < 4; nt++)
                acc[mt][nt] = __builtin_amdgcn_mfma_f32_16x16x32_bf16(a[mt], b[nt], acc[mt][nt], 0, 0, 0);
    }

#pragma unroll
    for (int mt = 0; mt < 4; mt++) {
        int row = m0 + wm * 64 + mt * 16 + quad * 4;
#pragma unroll
        for (int nt = 0; nt < 4; nt++) {
            int col = n0 + wn * 64 + nt * 16 + lane16;
            int qkv = (col >= 1536) ? 2 : ((col >= 768) ? 1 : 0);
            int rem = col - qkv * 768;
            int h = rem >> 6, e = rem & 63;
            short* dst = (qkv == 0) ? Qb : ((qkv == 1) ? Kb : Vb);
            float sc = (qkv == 0) ? (float)QSCALE : 1.0f;
            float bv = bias[col];
#pragma unroll
            for (int r = 0; r < 4; r++) {
                int i  = row + r;
                int b_ = i >> 11, s_ = i & 2047;
                dst[(((size_t)(b_ * 12 + h)) * 2048 + s_) * 64 + e] = f2bf((acc[mt][nt][r] + bv) * sc);
            }
        }
    }
}

// ---------------- V transpose + sigma key-permute: Vb [bh][s][64] -> Vt [bh][e][64-key tiles] ----------------
__global__ __launch_bounds__(256) void transpose_v(
    const short* __restrict__ Vb, short* __restrict__ Vt)
{
    __shared__ short T[64 * 66];
    int tid = threadIdx.x;
    int s0 = blockIdx.x * 64, bh = blockIdx.y;
    const short* src = Vb + (size_t)bh * 2048 * 64;
    short* dst = Vt + (size_t)bh * 64 * 2048;

#pragma unroll
    for (int i = 0; i < 2; i++) {
        int slot = i * 256 + tid;
        int s_loc = slot >> 3, ec = slot & 7;
        short8 v = *(const short8*)(src + (size_t)(s0 + s_loc) * 64 + ec * 8);
        *(short8*)(T + s_loc * 66 + ec * 8) = v;
    }
    __syncthreads();
#pragma unroll
    for (int i = 0; i < 2; i++) {
        int slot = i * 256 + tid;
        int e_loc = slot >> 3, sc = slot & 7;
        short8 o;
#pragma unroll
        for (int j = 0; j < 8; j++) {
            int p = sc * 8 + j;
            int kp = (p & 0x33) | ((p & 4) << 1) | ((p & 8) >> 1);   // sigma: swap bits 2,3
            o[j] = T[kp * 66 + e_loc];
        }
        *(short8*)(dst + (size_t)e_loc * 2048 + s0 + sc * 8) = o;
    }
}

// ---------------- flash attention, 32x32x16 MFMA, transposed QK^T, P in registers ----------------
// 64 q-rows PER WAVE (two q-groups sharing K/V fragments): 32 MFMA per 16 ds_read_b128 per
// tile (2x arithmetic intensity vs r0), 4 independent accumulator chains (2x ILP).
// 2-wave blocks of 128 threads, grid (16,48) = 768 blocks = 4/CU at 2 waves/SIMD.
// Schedule: simple 2-barrier staging (r1/r5 proved all schedule variants equivalent).
// XCD-aware remap (r4: attn FETCH 104->18.5 MB) + T5 setprio around MFMA clusters.
__global__ __launch_bounds__(128, 2) void attn(
    const short* __restrict__ Qb, const short* __restrict__ Kb,
    const short* __restrict__ Vt, short* __restrict__ Ctx)
{
    __shared__ short Ks[512 * 8];      // K tile: [key 64][e 64], swizzled slots
    __shared__ short Vs[512 * 8];      // V^T tile: [e 64][64 sigma-ordered keys], swizzled slots
    int tid = threadIdx.x, w = tid >> 6, l = tid & 63;
    int l32 = l & 31, half = l >> 5;

    int fid = blockIdx.x + (blockIdx.y << 4);   // 0..767, dispatch order
    int c = fid & 7, sfl = fid >> 3;            // sfl in 0..95
    int bh = c * 6 + (sfl >> 4);                // XCD c owns 6 heads
    int qt = sfl & 15;

    const short* Qh  = Qb + (size_t)bh * 2048 * 64;
    const short* Kh  = Kb + (size_t)bh * 2048 * 64;
    const short* Vth = Vt + (size_t)bh * 64 * 2048;
    int qbase = qt * 128 + w * 64;              // wave owns 64 q-rows

    // staging: 512 slots per array over 128 threads, 4 async16 per thread per array
    const short* kSrc[4];
    const short* vSrc[4];
    short* kDst[4];
    short* vDst[4];
#pragma unroll
    for (int i = 0; i < 4; i++) {
        int slot = i * 128 + tid;
        int row = slot >> 3;
        int g = (slot & 7) ^ (row & 7);
        kSrc[i] = Kh + (size_t)row * 64 + g * 8;        // + kt*64*64
        vSrc[i] = Vth + (size_t)row * 2048 + g * 8;     // + kt*64
        kDst[i] = Ks + (size_t)(i * 128 + w * 64) * 8;  // wave-uniform base
        vDst[i] = Vs + (size_t)(i * 128 + w * 64) * 8;
    }

    // Q fragments (B operand), two q-groups: lane holds q = qbase + qg*32 + l32
    short8 qf[2][4];
#pragma unroll
    for (int qg = 0; qg < 2; qg++)
#pragma unroll
        for (int ks = 0; ks < 4; ks++)
            qf[qg][ks] = *(const short8*)(Qh + (size_t)(qbase + qg * 32 + l32) * 64 + ks * 16 + half * 8);

    float lsum0 = 0.f, lsum1 = 0.f;
    floatx16 acc[2][2] = {};                    // [e-half][q-group]
    int sw = l32 & 7;   // row-swizzle term (row & 7 == l32 & 7 for row = nt*32 + l32)

    union upa { short8 s8; unsigned u[4]; };

    for (int kt = 0; kt < 32; kt++) {
        __syncthreads();
#pragma unroll
        for (int i = 0; i < 4; i++) {
            async16(kSrc[i] + (size_t)kt * 64 * 64, kDst[i]);
            async16(vSrc[i] + (size_t)kt * 64,      vDst[i]);
        }
        __syncthreads();

        // K fragments (A operand), shared by both q-groups
        short8 kf[2][4];
#pragma unroll
        for (int nt = 0; nt < 2; nt++) {
            int rowb = (nt * 32 + l32) * 8;
#pragma unroll
            for (int ks = 0; ks < 4; ks++)
                kf[nt][ks] = *(const short8*)(Ks + (size_t)(rowb + ((ks * 2 + half) ^ sw)) * 8);
        }

        // S^T for q-group 0: four independent chains total across qg (2 nt x 2 qg)
        floatx16 s[2];
        __builtin_amdgcn_s_setprio(1);
        {
            floatx16 c0 = {}, c1 = {};
#pragma unroll
            for (int ks = 0; ks < 4; ks++) {
                c0 = __builtin_amdgcn_mfma_f32_32x32x16_bf16(kf[0][ks], qf[0][ks], c0, 0, 0, 0);
                c1 = __builtin_amdgcn_mfma_f32_32x32x16_bf16(kf[1][ks], qf[0][ks], c1, 0, 0, 0);
            }
            s[0] = c0; s[1] = c1;
        }
        __builtin_amdgcn_s_setprio(0);

        upa pa0[4], pa1[4];
#pragma unroll
        for (int nt = 0; nt < 2; nt++)
#pragma unroll
            for (int r = 0; r < 16; r += 2) {
                float p0 = fast_exp2(s[nt][r]);
                float p1 = fast_exp2(s[nt][r + 1]);
                lsum0 += p0 + p1;
                pa0[2 * nt + (r >> 3)].u[(r & 7) >> 1] = pack2bf(p0, p1);
            }

        // S^T for q-group 1 (kf reused; can overlap qg0's exp2 in the scheduler)
        __builtin_amdgcn_s_setprio(1);
        {
            floatx16 c0 = {}, c1 = {};
#pragma unroll
            for (int ks = 0; ks < 4; ks++) {
                c0 = __builtin_amdgcn_mfma_f32_32x32x16_bf16(kf[0][ks], qf[1][ks], c0, 0, 0, 0);
                c1 = __builtin_amdgcn_mfma_f32_32x32x16_bf16(kf[1][ks], qf[1][ks], c1, 0, 0, 0);
            }
            s[0] = c0; s[1] = c1;
        }
        __builtin_amdgcn_s_setprio(0);

#pragma unroll
        for (int nt = 0; nt < 2; nt++)
#pragma unroll
            for (int r = 0; r < 16; r += 2) {
                float p0 = fast_exp2(s[nt][r]);
                float p1 = fast_exp2(s[nt][r + 1]);
                lsum1 += p0 + p1;
                pa1[2 * nt + (r >> 3)].u[(r & 7) >> 1] = pack2bf(p0, p1);
            }

        // V fragments (B operand), shared by both q-groups
        short8 vf[2][4];
#pragma unroll
        for (int ent = 0; ent < 2; ent++) {
            int rowb = (ent * 32 + l32) * 8;
#pragma unroll
            for (int ks = 0; ks < 4; ks++)
                vf[ent][ks] = *(const short8*)(Vs + (size_t)(rowb + ((ks * 2 + half) ^ sw)) * 8);
        }

        // PV: A = P (registers), B = V^T tile (sigma key order); 4 independent chains
        __builtin_amdgcn_s_setprio(1);
#pragma unroll
        for (int ent = 0; ent < 2; ent++)
#pragma unroll
            for (int ks = 0; ks < 4; ks++) {
                acc[ent][0] = __builtin_amdgcn_mfma_f32_32x32x16_bf16(pa0[ks].s8, vf[ent][ks], acc[ent][0], 0, 0, 0);
                acc[ent][1] = __builtin_amdgcn_mfma_f32_32x32x16_bf16(pa1[ks].s8, vf[ent][ks], acc[ent][1], 0, 0, 0);
            }
        __builtin_amdgcn_s_setprio(0);
    }

    // denominators: combine the two key-halves (lane and lane^32 hold same q, different keys)
    float den0 = lsum0 + __shfl_xor(lsum0, 32);
    float den1 = lsum1 + __shfl_xor(lsum1, 32);
    float inv0 = 1.0f / den0;
    float inv1 = 1.0f / den1;

    int b_ = bh / 12, h = bh % 12;
#pragma unroll
    for (int qg = 0; qg < 2; qg++)
#pragma unroll
        for (int ent = 0; ent < 2; ent++)
#pragma unroll
            for (int r = 0; r < 16; r++) {
                int qloc = (r & 3) + 8 * (r >> 2) + 4 * half;
                float invq = __shfl(qg ? inv1 : inv0, qloc);   // lane qloc holds q=qloc's inv denom
                int q = qbase + qg * 32 + qloc;
                int e = ent * 32 + l32;
                Ctx[((size_t)(b_ * 2048 + q)) * 768 + h * 64 + e] = f2bf(acc[ent][qg][r] * invq);
            }
}

// ---------------- proj GEMM: out[8192,768] = Ctx @ W2^T + b, fp32 out ----------------
// Tile 64(M) x 128(N): 768 blocks = exactly 3/CU. XCD remap: XCD c owns M-rows [16c,16c+16).
__global__ __launch_bounds__(256) void gemm_out(
    const short* __restrict__ Ctx, const short* __restrict__ W,
    const float* __restrict__ bias, float* __restrict__ out)
{
    __shared__ short As[64 * 32];
    __shared__ short Bs[128 * 32];
    int tid = threadIdx.x;
    int w = tid >> 6, l = tid & 63;
    int lane16 = l & 15, quad = l >> 4;
    int wm = w & 1, wn = w >> 1;

    int fid = blockIdx.x + 6 * blockIdx.y;    // 0..767
    int c = fid & 7, s = fid >> 3;            // s in 0..95
    int my = c * 16 + s / 6;                  // 0..127
    int nx = s % 6;                           // 0..5
    int m0 = my * 64, n0 = nx * 128;

    floatx4 acc[2][4] = {};

    int srow = tid >> 2;        // 0..63
    int scol = (tid & 3) * 8;
    const short* Xg = Ctx + (size_t)(m0 + srow) * KDIM + scol;
    const short* Wg = W + (size_t)(n0 + srow) * KDIM + scol;
    short* AsW = As + (w * 16) * 32;
    short* BsW = Bs + (w * 16) * 32;

    for (int kb = 0; kb < KDIM; kb += 32) {
        __syncthreads();
        async16(Xg + kb,             AsW);
        async16(Wg + kb,             BsW);
        async16(Wg + kb + 64 * KDIM, BsW + 64 * 32);
        __syncthreads();
        short8 a[2], b[4];
#pragma unroll
        for (int mt = 0; mt < 2; mt++) a[mt] = *(const short8*)(As + (wm * 32 + mt * 16 + lane16) * 32 + quad * 8);
#pragma unroll
        for (int nt = 0; nt < 4; nt++) b[nt] = *(const short8*)(Bs + (wn * 64 + nt * 16 + lane16) * 32 + quad * 8);
#pragma unroll
        for (int mt = 0; mt < 2; mt++)
#pragma unroll
            for (int nt = 0; nt < 4; nt++)
                acc[mt][nt] = __builtin_amdgcn_mfma_f32_16x16x32_bf16(a[mt], b[nt], acc[mt][nt], 0, 0, 0);
    }

#pragma unroll
    for (int mt = 0; mt < 2; mt++) {
        int row = m0 + wm * 32 + mt * 16 + quad * 4;
#pragma unroll
        for (int nt = 0; nt < 4; nt++) {
            int col = n0 + wn * 64 + nt * 16 + lane16;
            float bv = bias[col];
#pragma unroll
            for (int r = 0; r < 4; r++)
                out[(size_t)(row + r) * 768 + col] = acc[mt][nt][r] + bv;
        }
    }
}

extern "C" void kernel_launch(void* const* d_in, const int* in_sizes, int n_in,
                              void* d_out, int out_size, void* d_ws, size_t ws_size,
                              hipStream_t stream) {
    const float* hs     = (const float*)d_in[0];
    const float* qkv_w  = (const float*)d_in[1];
    const float* qkv_b  = (const float*)d_in[2];
    const float* proj_w = (const float*)d_in[3];
    const float* proj_b = (const float*)d_in[4];
    float* out = (float*)d_out;

    short* Xb  = (short*)d_ws;                     // 8192*768 (dead after gemm_qkv; reused as Vt)
    short* W1b = Xb  + (size_t)8192 * 768;         // 2304*768
    short* W2b = W1b + (size_t)2304 * 768;         // 768*768
    short* Qb  = W2b + (size_t)768 * 768;          // 48*2048*64
    short* Kb  = Qb  + (size_t)8192 * 768;
    short* Vb  = Kb  + (size_t)8192 * 768;
    short* Ctx = Vb  + (size_t)8192 * 768;         // 8192*768
    short* Vt  = Xb;                               // [bh][64][2048] sigma-ordered, overlays dead Xb

    int ntot = (N1 + N2 + N3) / 4;
    cvt_all<<<(ntot + 255) / 256, 256, 0, stream>>>(hs, qkv_w, proj_w, Xb, W1b, W2b);

    gemm_qkv<<<dim3(18, 64), 256, 0, stream>>>(Xb, W1b, qkv_b, Qb, Kb, Vb);
    transpose_v<<<dim3(32, 48), 256, 0, stream>>>(Vb, Vt);
    attn<<<dim3(16, 48), 128, 0, stream>>>(Qb, Kb, Vt, Ctx);
    gemm_out<<<dim3(6, 128), 256, 0, stream>>>(Ctx, W2b, proj_b, out);
}

// Round 7
// 218.581 us; speedup vs baseline: 1.2801x; 1.2801x over previous
//
#include <hip/hip_runtime.h>
#include <hip/hip_bf16.h>

using short8   = __attribute__((ext_vector_type(8))) short;
using floatx4  = __attribute__((ext_vector_type(4))) float;
using floatx16 = __attribute__((ext_vector_type(16))) float;

#define KDIM 768
#define QSCALE 0.18033688011112042f   // 0.125 * log2(e)
#define N1 (8192 * 768)
#define N2 (2304 * 768)
#define N3 (768 * 768)

__device__ __forceinline__ short f2bf(float f) {
    union { float f; unsigned u; } v; v.f = f;
    unsigned r = v.u + 0x7fffu + ((v.u >> 16) & 1u);
    return (short)(r >> 16);
}

__device__ __forceinline__ unsigned pack2bf(float a, float b) {
    __hip_bfloat162 h = __float22bfloat162_rn(float2{a, b});
    union { __hip_bfloat162 h; unsigned u; } c; c.h = h;
    return c.u;
}

__device__ __forceinline__ float fast_exp2(float x) {
#if __has_builtin(__builtin_amdgcn_exp2f)
    return __builtin_amdgcn_exp2f(x);
#else
    return exp2f(x);
#endif
}

__device__ __forceinline__ void async16(const void* g, void* l) {
    __builtin_amdgcn_global_load_lds((const __attribute__((address_space(1))) void*)g,
                                     (__attribute__((address_space(3))) void*)l, 16, 0, 0);
}

// ---------------- fused fp32 -> bf16 convert for all three inputs ----------------
__global__ void cvt_all(const float* __restrict__ a, const float* __restrict__ b,
                        const float* __restrict__ c, short* __restrict__ oa,
                        short* __restrict__ ob, short* __restrict__ oc) {
    int i = (blockIdx.x * blockDim.x + threadIdx.x) * 4;
    const float* src; short* dst;
    if (i < N1)            { src = a + i;            dst = oa + i; }
    else if (i < N1 + N2)  { src = b + (i - N1);     dst = ob + (i - N1); }
    else if (i < N1+N2+N3) { src = c + (i - N1 - N2); dst = oc + (i - N1 - N2); }
    else return;
    float4 v = *(const float4*)src;
    short4 o;
    o.x = f2bf(v.x); o.y = f2bf(v.y); o.z = f2bf(v.z); o.w = f2bf(v.w);
    *(short4*)dst = o;
}

// ---------------- QKV GEMM: C[8192,2304] = X @ W^T, scatter to Q/K/V [bh][s][64] ----------------
// XCD-aware remap: XCD c = fid%8 owns M-rows [8c, 8c+8).
// Epilogue v2: C-tile staged through LDS, written back as coalesced 16B/lane stores
// (old epilogue: 64 scattered 2B stores/thread = 24.8M scalar stores kernel-wide).
// Each 128-col block is entirely one of Q/K/V (768 % 128 == 0), covering 2 heads;
// a [s][64] head-slab is contiguous in the [bh][s][64] layout -> perfect coalescing.
__global__ __launch_bounds__(256) void gemm_qkv(
    const short* __restrict__ X, const short* __restrict__ W,
    const float* __restrict__ bias,
    short* __restrict__ Qb, short* __restrict__ Kb, short* __restrict__ Vb)
{
    __shared__ short Smem[128 * 144];          // 36 KB: As/Bs (16 KB) during K-loop, C-tile after
    short* As = Smem;                          // 128*32
    short* Bs = Smem + 128 * 32;               // 128*32
    int tid = threadIdx.x;
    int w = tid >> 6, l = tid & 63;
    int lane16 = l & 15, quad = l >> 4;
    int wm = w & 1, wn = w >> 1;

    int fid = blockIdx.x + 18 * blockIdx.y;   // 0..1151, dispatch order
    int c = fid & 7, s = fid >> 3;            // s in 0..143
    int my = c * 8 + s / 18;                  // 0..63
    int nx = s % 18;                          // 0..17
    int m0 = my * 128, n0 = nx * 128;

    floatx4 acc[4][4] = {};

    int srow = w * 32 + (l >> 2);
    int scol = (l & 3) * 8;
    const short* Xg = X + (size_t)(m0 + srow) * KDIM + scol;
    const short* Wg = W + (size_t)(n0 + srow) * KDIM + scol;
    short* AsW = As + (w * 32) * 32;
    short* BsW = Bs + (w * 32) * 32;

    for (int kb = 0; kb < KDIM; kb += 32) {
        __syncthreads();
        async16(Xg + kb,              AsW);
        async16(Xg + kb + 16 * KDIM,  AsW + 16 * 32);
        async16(Wg + kb,              BsW);
        async16(Wg + kb + 16 * KDIM,  BsW + 16 * 32);
        __syncthreads();
        short8 a[4], b[4];
#pragma unroll
        for (int mt = 0; mt < 4; mt++) a[mt] = *(const short8*)(As + (wm * 64 + mt * 16 + lane16) * 32 + quad * 8);
#pragma unroll
        for (int nt = 0; nt < 4; nt++) b[nt] = *(const short8*)(Bs + (wn * 64 + nt * 16 + lane16) * 32 + quad * 8);
#pragma unroll
        for (int mt = 0; mt < 4; mt++)
#pragma unroll
            for (int nt = 0; nt < 4; nt++)
                acc[mt][nt] = __builtin_amdgcn_mfma_f32_16x16x32_bf16(a[mt], b[nt], acc[mt][nt], 0, 0, 0);
    }

    // ---- epilogue: acc -> LDS (bias + scale + bf16) -> coalesced global writes ----
    int qkv = nx / 6;                          // whole block is one of Q/K/V
    float sc = (qkv == 0) ? (float)QSCALE : 1.0f;
    short* dst = (qkv == 0) ? Qb : ((qkv == 1) ? Kb : Vb);
    int h0 = (nx - qkv * 6) * 2;               // first of the 2 heads this block covers
    int b_ = m0 >> 11, s0 = m0 & 2047;

    __syncthreads();                           // all MFMA reads of As/Bs complete
#pragma unroll
    for (int mt = 0; mt < 4; mt++) {
        int rowl = wm * 64 + mt * 16 + quad * 4;
#pragma unroll
        for (int nt = 0; nt < 4; nt++) {
            int coll = wn * 64 + nt * 16 + lane16;
            float bv = bias[n0 + coll];
#pragma unroll
            for (int r = 0; r < 4; r++)
                Smem[(rowl + r) * 144 + coll] = f2bf((acc[mt][nt][r] + bv) * sc);
        }
    }
    __syncthreads();
    // write-back: 16384 shorts = 2048 short8 slots over 256 threads
#pragma unroll
    for (int i = 0; i < 8; i++) {
        int slot = i * 256 + tid;
        int ch = slot >> 10;                   // which head (0/1)
        int rem2 = slot & 1023;
        int s_loc = rem2 >> 3, e8 = rem2 & 7;
        short8 v = *(const short8*)(Smem + s_loc * 144 + ch * 64 + e8 * 8);
        *(short8*)(dst + (((size_t)(b_ * 12 + h0 + ch)) * 2048 + s0 + s_loc) * 64 + e8 * 8) = v;
    }
}

// ---------------- V transpose + sigma key-permute: Vb [bh][s][64] -> Vt [bh][e][64-key tiles] ----------------
__global__ __launch_bounds__(256) void transpose_v(
    const short* __restrict__ Vb, short* __restrict__ Vt)
{
    __shared__ short T[64 * 66];
    int tid = threadIdx.x;
    int s0 = blockIdx.x * 64, bh = blockIdx.y;
    const short* src = Vb + (size_t)bh * 2048 * 64;
    short* dst = Vt + (size_t)bh * 64 * 2048;

#pragma unroll
    for (int i = 0; i < 2; i++) {
        int slot = i * 256 + tid;
        int s_loc = slot >> 3, ec = slot & 7;
        short8 v = *(const short8*)(src + (size_t)(s0 + s_loc) * 64 + ec * 8);
        *(short8*)(T + s_loc * 66 + ec * 8) = v;
    }
    __syncthreads();
#pragma unroll
    for (int i = 0; i < 2; i++) {
        int slot = i * 256 + tid;
        int e_loc = slot >> 3, sc = slot & 7;
        short8 o;
#pragma unroll
        for (int j = 0; j < 8; j++) {
            int p = sc * 8 + j;
            int kp = (p & 0x33) | ((p & 4) << 1) | ((p & 8) >> 1);   // sigma: swap bits 2,3
            o[j] = T[kp * 66 + e_loc];
        }
        *(short8*)(dst + (size_t)e_loc * 2048 + s0 + sc * 8) = o;
    }
}

// ---------------- flash attention, 32x32x16 MFMA, transposed QK^T, P in registers ----------------
// r5 kernel verbatim (best measured 72.1-72.6 us): grid (16,48), 4 waves, 32 q-rows/wave,
// triple-buffered K/V, depth-2 prefetch, one s_barrier + counted vmcnt(4) per tile,
// XCD-aware remap (FETCH 104->18.5 MB), setprio around MFMA clusters.
__global__ __launch_bounds__(256, 3) void attn(
    const short* __restrict__ Qb, const short* __restrict__ Kb,
    const short* __restrict__ Vt, short* __restrict__ Ctx)
{
    __shared__ short Ks[3][512 * 8];   // K tiles: [key 64][e 64], swizzled slots, 3 buffers
    __shared__ short Vs[3][512 * 8];   // V^T tiles: [e 64][64 sigma-ordered keys], 3 buffers
    int tid = threadIdx.x, w = tid >> 6, l = tid & 63;
    int l32 = l & 31, half = l >> 5;

    int fid = blockIdx.x + (blockIdx.y << 4);   // 0..767, dispatch order
    int c = fid & 7, sfl = fid >> 3;            // sfl in 0..95
    int bh = c * 6 + (sfl >> 4);                // XCD c owns 6 heads
    int qt = sfl & 15;

    const short* Qh  = Qb + (size_t)bh * 2048 * 64;
    const short* Kh  = Kb + (size_t)bh * 2048 * 64;
    const short* Vth = Vt + (size_t)bh * 64 * 2048;
    int qbase = qt * 128 + w * 32;

    // staging geometry: 512 slots per array over 256 threads, 2 async16 each
    const short* kSrc[2];
    const short* vSrc[2];
    int dOff[2];
#pragma unroll
    for (int i = 0; i < 2; i++) {
        int slot = i * 256 + tid;
        int row = slot >> 3;
        int g = (slot & 7) ^ (row & 7);
        kSrc[i] = Kh + (size_t)row * 64 + g * 8;        // + kt*64*64
        vSrc[i] = Vth + (size_t)row * 2048 + g * 8;     // + kt*64
        dOff[i] = (i * 256 + w * 64) * 8;               // wave-uniform base (shorts)
    }

    // Q fragments (B operand): lane holds q = qbase + l32, k = e
    short8 qf[4];
#pragma unroll
    for (int ks = 0; ks < 4; ks++)
        qf[ks] = *(const short8*)(Qh + (size_t)(qbase + l32) * 64 + ks * 16 + half * 8);

    // prologue: stage tiles 0 and 1 into buffers 0 and 1
#pragma unroll
    for (int i = 0; i < 2; i++) {
        async16(kSrc[i],                  &Ks[0][0] + dOff[i]);
        async16(vSrc[i],                  &Vs[0][0] + dOff[i]);
    }
#pragma unroll
    for (int i = 0; i < 2; i++) {
        async16(kSrc[i] + 4096,           &Ks[1][0] + dOff[i]);
        async16(vSrc[i] + 64,             &Vs[1][0] + dOff[i]);
    }

    float lsum = 0.f;
    floatx16 acc[2] = {};
    int sw = l32 & 7;   // row-swizzle term (row & 7 == l32 & 7 for row = nt*32 + l32)

    int cur = 0;        // kt % 3, maintained incrementally
    for (int kt = 0; kt < 32; kt++) {
        // counted wait: tile kt's 4 loads landed (kt+1's 4 stay in flight); last tile drains
        if (kt < 31) { asm volatile("s_waitcnt vmcnt(4)" ::: "memory"); }
        else         { asm volatile("s_waitcnt vmcnt(0)" ::: "memory"); }
        __builtin_amdgcn_s_barrier();     // all waves' tile-kt loads visible; buf reuse safe

        // issue tile kt+2's stage into buffer (kt+2)%3  (lands ~2 tiles from now)
        int pf = kt + 2;
        if (pf < 32) {
            int pb = cur >= 1 ? cur - 1 : cur + 2;    // (kt+2)%3 == (kt-1)%3
#pragma unroll
            for (int i = 0; i < 2; i++) {
                async16(kSrc[i] + (size_t)pf * 4096, &Ks[pb][0] + dOff[i]);
                async16(vSrc[i] + (size_t)pf * 64,   &Vs[pb][0] + dOff[i]);
            }
        }

        const short* Kcur = &Ks[cur][0];
        const short* Vcur = &Vs[cur][0];

        // S^T: A = K-frag (m = key), B = Q-frag (n = q) -> col = q = l32
        floatx16 s[2];
        __builtin_amdgcn_s_setprio(1);
#pragma unroll
        for (int nt = 0; nt < 2; nt++) {
            floatx16 cacc = {};
            int rowb = (nt * 32 + l32) * 8;
#pragma unroll
            for (int ks = 0; ks < 4; ks++) {
                short8 kf = *(const short8*)(Kcur + (size_t)(rowb + ((ks * 2 + half) ^ sw)) * 8);
                cacc = __builtin_amdgcn_mfma_f32_32x32x16_bf16(kf, qf[ks], cacc, 0, 0, 0);
            }
            s[nt] = cacc;
        }
        __builtin_amdgcn_s_setprio(0);

        // exp2 + row-sum + pack P into A-fragments in registers:
        // reg (nt, r) -> pa[2*nt + (r>>3)], element j = r&7
        union { short8 s8; unsigned u[4]; } pa[4];
#pragma unroll
        for (int nt = 0; nt < 2; nt++)
#pragma unroll
            for (int r = 0; r < 16; r += 2) {
                float p0 = fast_exp2(s[nt][r]);
                float p1 = fast_exp2(s[nt][r + 1]);
                lsum += p0 + p1;
                pa[2 * nt + (r >> 3)].u[(r & 7) >> 1] = pack2bf(p0, p1);
            }

        // PV: A = P (registers), B = V^T tile (sigma key order)
        __builtin_amdgcn_s_setprio(1);
#pragma unroll
        for (int nt = 0; nt < 2; nt++) {
            int rowb = (nt * 32 + l32) * 8;
#pragma unroll
            for (int ks = 0; ks < 4; ks++) {
                short8 vf = *(const short8*)(Vcur + (size_t)(rowb + ((ks * 2 + half) ^ sw)) * 8);
                acc[nt] = __builtin_amdgcn_mfma_f32_32x32x16_bf16(pa[ks].s8, vf, acc[nt], 0, 0, 0);
            }
        }
        __builtin_amdgcn_s_setprio(0);

        cur = (cur == 2) ? 0 : cur + 1;
    }

    // denominator for q = l32 (this lane's own q-row): combine the two halves
    float denom = lsum + __shfl_xor(lsum, 32);
    float inv_self = 1.0f / denom;

    int b_ = bh / 12, h = bh % 12;
#pragma unroll
    for (int nt = 0; nt < 2; nt++)
#pragma unroll
        for (int r = 0; r < 16; r++) {
            int qloc = (r & 3) + 8 * (r >> 2) + 4 * half;
            float invq = __shfl(inv_self, qloc);   // lane qloc holds q=qloc's inverse denom
            int q = qbase + qloc;
            int e = nt * 32 + l32;
            Ctx[((size_t)(b_ * 2048 + q)) * 768 + h * 64 + e] = f2bf(acc[nt][r] * invq);
        }
}

// ---------------- proj GEMM: out[8192,768] = Ctx @ W2^T + b, fp32 out ----------------
// Tile 64(M) x 128(N): 768 blocks = exactly 3/CU. XCD remap: XCD c owns M-rows [16c,16c+16).
__global__ __launch_bounds__(256) void gemm_out(
    const short* __restrict__ Ctx, const short* __restrict__ W,
    const float* __restrict__ bias, float* __restrict__ out)
{
    __shared__ short As[64 * 32];
    __shared__ short Bs[128 * 32];
    int tid = threadIdx.x;
    int w = tid >> 6, l = tid & 63;
    int lane16 = l & 15, quad = l >> 4;
    int wm = w & 1, wn = w >> 1;

    int fid = blockIdx.x + 6 * blockIdx.y;    // 0..767
    int c = fid & 7, s = fid >> 3;            // s in 0..95
    int my = c * 16 + s / 6;                  // 0..127
    int nx = s % 6;                           // 0..5
    int m0 = my * 64, n0 = nx * 128;

    floatx4 acc[2][4] = {};

    int srow = tid >> 2;        // 0..63
    int scol = (tid & 3) * 8;
    const short* Xg = Ctx + (size_t)(m0 + srow) * KDIM + scol;
    const short* Wg = W + (size_t)(n0 + srow) * KDIM + scol;
    short* AsW = As + (w * 16) * 32;
    short* BsW = Bs + (w * 16) * 32;

    for (int kb = 0; kb < KDIM; kb += 32) {
        __syncthreads();
        async16(Xg + kb,             AsW);
        async16(Wg + kb,             BsW);
        async16(Wg + kb + 64 * KDIM, BsW + 64 * 32);
        __syncthreads();
        short8 a[2], b[4];
#pragma unroll
        for (int mt = 0; mt < 2; mt++) a[mt] = *(const short8*)(As + (wm * 32 + mt * 16 + lane16) * 32 + quad * 8);
#pragma unroll
        for (int nt = 0; nt < 4; nt++) b[nt] = *(const short8*)(Bs + (wn * 64 + nt * 16 + lane16) * 32 + quad * 8);
#pragma unroll
        for (int mt = 0; mt < 2; mt++)
#pragma unroll
            for (int nt = 0; nt < 4; nt++)
                acc[mt][nt] = __builtin_amdgcn_mfma_f32_16x16x32_bf16(a[mt], b[nt], acc[mt][nt], 0, 0, 0);
    }

#pragma unroll
    for (int mt = 0; mt < 2; mt++) {
        int row = m0 + wm * 32 + mt * 16 + quad * 4;
#pragma unroll
        for (int nt = 0; nt < 4; nt++) {
            int col = n0 + wn * 64 + nt * 16 + lane16;
            float bv = bias[col];
#pragma unroll
            for (int r = 0; r < 4; r++)
                out[(size_t)(row + r) * 768 + col] = acc[mt][nt][r] + bv;
        }
    }
}

extern "C" void kernel_launch(void* const* d_in, const int* in_sizes, int n_in,
                              void* d_out, int out_size, void* d_ws, size_t ws_size,
                              hipStream_t stream) {
    const float* hs     = (const float*)d_in[0];
    const float* qkv_w  = (const float*)d_in[1];
    const float* qkv_b  = (const float*)d_in[2];
    const float* proj_w = (const float*)d_in[3];
    const float* proj_b = (const float*)d_in[4];
    float* out = (float*)d_out;

    short* Xb  = (short*)d_ws;                     // 8192*768 (dead after gemm_qkv; reused as Vt)
    short* W1b = Xb  + (size_t)8192 * 768;         // 2304*768
    short* W2b = W1b + (size_t)2304 * 768;         // 768*768
    short* Qb  = W2b + (size_t)768 * 768;          // 48*2048*64
    short* Kb  = Qb  + (size_t)8192 * 768;
    short* Vb  = Kb  + (size_t)8192 * 768;
    short* Ctx = Vb  + (size_t)8192 * 768;         // 8192*768
    short* Vt  = Xb;                               // [bh][64][2048] sigma-ordered, overlays dead Xb

    int ntot = (N1 + N2 + N3) / 4;
    cvt_all<<<(ntot + 255) / 256, 256, 0, stream>>>(hs, qkv_w, proj_w, Xb, W1b, W2b);

    gemm_qkv<<<dim3(18, 64), 256, 0, stream>>>(Xb, W1b, qkv_b, Qb, Kb, Vb);
    transpose_v<<<dim3(32, 48), 256, 0, stream>>>(Vb, Vt);
    attn<<<dim3(16, 48), 256, 0, stream>>>(Qb, Kb, Vt, Ctx);
    gemm_out<<<dim3(6, 128), 256, 0, stream>>>(Ctx, W2b, proj_b, out);
}